// Round 5
// baseline (35.199 us; speedup 1.0000x reference)
//
#include <hip/hip_runtime.h>
#include <stdint.h>
#include <math.h>

#define BN 16
#define LATN 64
#define STATSN 7
#define ZN 71
#define HN 128
#define H2N 256
#define NNODE 256
#define NPAIR 32640            // N*(N-1)/2
#define NQ 522240              // BN*NPAIR

// Raw barrier: drain LDS only (lgkmcnt), leave global prefetches (vmcnt) in
// flight across the barrier. Single asm block so no memory op can be
// scheduled between the waitcnt and the s_barrier; "memory" clobber pins
// LDS writes above and LDS reads below. (__syncthreads would drain vmcnt(0)
// and kill cross-phase weight prefetch.)
#define BARRIER() asm volatile("s_waitcnt lgkmcnt(0)\n\ts_barrier" ::: "memory")

// ---------------- Threefry-2x32, 20 rounds, key = (0, 42) ----------------
__device__ __forceinline__ void tf2x32(uint32_t x0, uint32_t x1,
                                       uint32_t& o0, uint32_t& o1) {
    const uint32_t ks0 = 0u, ks1 = 42u, ks2 = 0x1BD11BF0u;  // 0^42^0x1BD11BDA
    x0 += ks0; x1 += ks1;
#define TFRND(r) { x0 += x1; x1 = (x1 << (r)) | (x1 >> (32 - (r))); x1 ^= x0; }
    TFRND(13) TFRND(15) TFRND(26) TFRND(6)
    x0 += ks1; x1 += ks2 + 1u;
    TFRND(17) TFRND(29) TFRND(16) TFRND(24)
    x0 += ks2; x1 += ks0 + 2u;
    TFRND(13) TFRND(15) TFRND(26) TFRND(6)
    x0 += ks0; x1 += ks1 + 3u;
    TFRND(17) TFRND(29) TFRND(16) TFRND(24)
    x0 += ks1; x1 += ks2 + 4u;
    TFRND(13) TFRND(15) TFRND(26) TFRND(6)
    x0 += ks2; x1 += ks0 + 5u;
#undef TFRND
    o0 = x0; o1 = x1;
}

__device__ __forceinline__ uint32_t bits_partitionable(uint32_t m) {
    uint32_t o0, o1;
    tf2x32(0u, m, o0, o1);
    return o0 ^ o1;
}

__device__ __forceinline__ float bits_to_u(uint32_t w) {
    float f = __uint_as_float((w >> 9) | 0x3f800000u) - 1.0f;
    const float mn = 1e-9f;
    return fmaxf(mn, f * (1.0f - mn) + mn);
}

// ---------------- register-resident weight slice ----------------
// 1024 threads = O outputs x C k-chunks; each thread holds KC weights in regs.
template<int K, int O>
struct WSlice {
    static constexpr int C    = 1024 / O;
    static constexpr int KC   = (K + C - 1) / C;
    static constexpr int LOGO = (O == 256) ? 8 : 7;
    float w[KC];
    __device__ __forceinline__ void load(const float* __restrict__ W, int t) {
        const int out = t & (O - 1);
        const int k0 = (t >> LOGO) * KC;
#pragma unroll
        for (int i = 0; i < KC; ++i) {
            const int k = k0 + i;
            w[i] = ((K % C == 0) || k < K) ? W[k * O + out] : 0.0f;
        }
    }
    // identical fma pairing + summation order to the verified round-3 mm()
    __device__ __forceinline__ double dot(const float* __restrict__ vin, int t) const {
        const int k0 = (t >> LOGO) * KC;
        double a0 = 0.0, a1 = 0.0;
#pragma unroll
        for (int i = 0; i < KC; i += 2) {
            a0 = fma((double)vin[k0 + i], (double)w[i], a0);
            if (i + 1 < KC) a1 = fma((double)vin[k0 + i + 1], (double)w[i + 1], a1);
        }
        return a0 + a1;
    }
    // edge_in = [hf, hf]: read vin[(k)&127] (no LDS duplication barrier)
    __device__ __forceinline__ double dot_mask127(const float* __restrict__ vin, int t) const {
        const int k0 = (t >> LOGO) * KC;
        double a0 = 0.0, a1 = 0.0;
#pragma unroll
        for (int i = 0; i < KC; i += 2) {
            a0 = fma((double)vin[(k0 + i) & 127], (double)w[i], a0);
            if (i + 1 < KC) a1 = fma((double)vin[(k0 + i + 1) & 127], (double)w[i + 1], a1);
        }
        return a0 + a1;
    }
};

// fused LayerNorm stats (single pass: sum + sumsq reduced as a pair)
template<int O>
__device__ __forceinline__ float ln_apply(float v, int t, double* red) {
    constexpr int NW = O / 64;
    double a = (t < O) ? (double)v : 0.0;
    double q = a * a;
#pragma unroll
    for (int s = 32; s > 0; s >>= 1) {
        a += __shfl_down(a, s, 64);
        q += __shfl_down(q, s, 64);
    }
    const int wid = t >> 6, lane = t & 63;
    if (wid < NW && lane == 0) { red[2 * wid] = a; red[2 * wid + 1] = q; }
    BARRIER();
    double sa = 0.0, sq = 0.0;
#pragma unroll
    for (int i = 0; i < NW; ++i) { sa += red[2 * i]; sq += red[2 * i + 1]; }
    const double m = sa * (1.0 / (double)O);
    const double var = sq * (1.0 / (double)O) - m * m;
    const double rs = 1.0 / sqrt(var + 1e-5);
    return (float)(((double)v - m) * rs);
}

__global__ __launch_bounds__(1024) void logits_kernel(
    const float* __restrict__ x, const float* __restrict__ st,
    const float* __restrict__ ipw, const float* __restrict__ ipb,
    const float* __restrict__ ipg, const float* __restrict__ ipbb,
    const float* __restrict__ drw, const float* __restrict__ drb,
    const float* __restrict__ drg, const float* __restrict__ drbb,
    const float* __restrict__ r1w, const float* __restrict__ r1b,
    const float* __restrict__ r2w, const float* __restrict__ r2b,
    const float* __restrict__ n1g, const float* __restrict__ n1b,
    const float* __restrict__ n2g, const float* __restrict__ n2b,
    const float* __restrict__ e1w, const float* __restrict__ e1b,
    const float* __restrict__ eg,  const float* __restrict__ eb,
    const float* __restrict__ e2w, const float* __restrict__ e2b,
    float* __restrict__ out_logits)
{
    __shared__ float V0[H2N];
    __shared__ float V1[H2N];
    __shared__ double dpart[1024];
    __shared__ double red[8];
    const int t = threadIdx.x;
    const int b = blockIdx.x;
    const int t255 = t & 255, t127 = t & 127;

    // -------- prologue: issue weight/bias prefetches, stage z --------
    WSlice<ZN, H2N> w_ip;  w_ip.load(ipw, t);
    const float ipb_r  = ipb[t255],  ipg_r = ipg[t255],  ipbb_r = ipbb[t255];
    const float drb_r  = drb[t127],  drg_r = drg[t127],  drbb_r = drbb[t127];
    const float b1a = r1b[t127],       g1a = n1g[t127],       c1a = n1b[t127];
    const float g2a = n2g[t127],       c2a = n2b[t127],       b2a = r2b[t127];
    const float b1b = r1b[128 + t127], g1b = n1g[128 + t127], c1b = n1b[128 + t127];
    const float g2b = n2g[128 + t127], c2b = n2b[128 + t127], b2b = r2b[128 + t127];
    const float e1b_r = e1b[t127], eg_r = eg[t127], eb_r = eb[t127];
    const float e2w_r = e2w[t255];  // e2w[(t>>1)*2 + (t&1)] == e2w[t]

    if (t < LATN)      V0[t] = x[b * LATN + t];
    else if (t < ZN)   V0[t] = st[b * STATSN + (t - LATN)];
    else if (t < H2N)  V0[t] = 0.0f;   // zero-pad so padded w entries multiply 0, not junk
    BARRIER();

    // -------- input_proj: [71]->relu->LN(256) -> V1 --------
    WSlice<H2N, HN> w_dr;  w_dr.load(drw, t);   // prefetch next phase
    {
        double acc = w_ip.dot(V0, t);
        dpart[t] = acc;
        BARRIER();
        float v = 0.0f;
        const bool act = t < H2N;
        if (act) {
            double ca = 0.0;
#pragma unroll
            for (int cc = 0; cc < WSlice<ZN, H2N>::C; ++cc) ca += dpart[t + cc * H2N];
            v = fmaxf((float)ca + ipb_r, 0.0f);
        }
        float r = ln_apply<H2N>(v, t, red);
        if (act) V1[t] = r * ipg_r + ipbb_r;
    }
    BARRIER();

    // -------- dim_reduce: [256]->[128], relu, LN -> V0 --------
    WSlice<HN, HN> w_r1a;  w_r1a.load(r1w, t);   // prefetch
    {
        double acc = w_dr.dot(V1, t);
        dpart[t] = acc;
        BARRIER();
        float v = 0.0f;
        const bool act = t < HN;
        if (act) {
            double ca = 0.0;
#pragma unroll
            for (int cc = 0; cc < WSlice<H2N, HN>::C; ++cc) ca += dpart[t + cc * HN];
            v = fmaxf((float)ca + drb_r, 0.0f);
        }
        float r = ln_apply<HN>(v, t, red);
        if (act) V0[t] = r * drg_r + drbb_r;
    }
    BARRIER();

    // -------- residual block 0 --------
    WSlice<HN, HN> w_r2a;  w_r2a.load(r2w, t);   // prefetch
    float hval = (t < HN) ? V0[t] : 0.0f;
    {   // LN1
        float r = ln_apply<HN>(hval, t, red);
        if (t < HN) V1[t] = r * g1a + c1a;
    }
    BARRIER();
    WSlice<HN, HN> w_r1b;  w_r1b.load(r1w + HN * HN, t);   // prefetch
    {   // lin1 + relu + LN2
        double acc = w_r1a.dot(V1, t);
        dpart[t] = acc;
        BARRIER();
        float v = 0.0f;
        if (t < HN) {
            double ca = 0.0;
#pragma unroll
            for (int cc = 0; cc < WSlice<HN, HN>::C; ++cc) ca += dpart[t + cc * HN];
            v = fmaxf((float)ca + b1a, 0.0f);
        }
        float r = ln_apply<HN>(v, t, red);
        if (t < HN) V1[t] = r * g2a + c2a;
    }
    BARRIER();
    WSlice<HN, HN> w_r2b;  w_r2b.load(r2w + HN * HN, t);   // prefetch
    {   // lin2 + residual
        double acc = w_r2a.dot(V1, t);
        dpart[t] = acc;
        BARRIER();
        if (t < HN) {
            double ca = 0.0;
#pragma unroll
            for (int cc = 0; cc < WSlice<HN, HN>::C; ++cc) ca += dpart[t + cc * HN];
            float r2o = (float)ca + b2a;
            V0[t] = hval + 0.1f * (r2o + hval);
        }
    }
    BARRIER();

    // -------- residual block 1 --------
    hval = (t < HN) ? V0[t] : 0.0f;
    {   // LN1
        float r = ln_apply<HN>(hval, t, red);
        if (t < HN) V1[t] = r * g1b + c1b;
    }
    BARRIER();
    WSlice<H2N, HN> w_e1;  w_e1.load(e1w, t);   // prefetch edge MLP
    {   // lin1 + relu + LN2
        double acc = w_r1b.dot(V1, t);
        dpart[t] = acc;
        BARRIER();
        float v = 0.0f;
        if (t < HN) {
            double ca = 0.0;
#pragma unroll
            for (int cc = 0; cc < WSlice<HN, HN>::C; ++cc) ca += dpart[t + cc * HN];
            v = fmaxf((float)ca + b1b, 0.0f);
        }
        float r = ln_apply<HN>(v, t, red);
        if (t < HN) V1[t] = r * g2b + c2b;
    }
    BARRIER();
    {   // lin2 + residual
        double acc = w_r2b.dot(V1, t);
        dpart[t] = acc;
        BARRIER();
        if (t < HN) {
            double ca = 0.0;
#pragma unroll
            for (int cc = 0; cc < WSlice<HN, HN>::C; ++cc) ca += dpart[t + cc * HN];
            float r2o = (float)ca + b2b;
            V0[t] = hval + 0.1f * (r2o + hval);
        }
    }
    BARRIER();

    // -------- attention uniform (exact 1/256) + edge MLP e1 --------
    {
        // edge_in[k] = (h*(1/256))[k & 127]; scale applied after the dot (exact pow2)
        double acc = w_e1.dot_mask127(V0, t) * 0.00390625;
        dpart[t] = acc;
        BARRIER();
        float v = 0.0f;
        if (t < HN) {
            double ca = 0.0;
#pragma unroll
            for (int cc = 0; cc < WSlice<H2N, HN>::C; ++cc) ca += dpart[t + cc * HN];
            v = fmaxf((float)ca + e1b_r, 0.0f);
        }
        float r = ln_apply<HN>(v, t, red);
        if (t < HN) V0[t] = r * eg_r + eb_r;
    }
    BARRIER();

    // -------- e2: [128]->[2] (identical arithmetic to round 3) --------
    {
        if (t < 256) {
            const int c = t >> 1;
            double p = (double)V0[c] * (double)e2w_r;
#pragma unroll
            for (int s = 32; s > 1; s >>= 1) p += __shfl_down(p, s, 64);
            const int wid = t >> 6, lane = t & 63;
            if (lane < 2) dpart[wid * 2 + lane] = p;
        }
        BARRIER();
        if (t < 2) {
            double acc = 0.0;
#pragma unroll
            for (int c2 = 0; c2 < 4; ++c2) acc += dpart[c2 * 2 + t];
            out_logits[b * 2 + t] = (float)acc + e2b[t];
        }
    }
}

// ---------------- per-pair gumbel decisions + scatter ----------------
__device__ __forceinline__ int rowbase(int i) { return (i * (2 * NNODE - 1 - i)) >> 1; }

__global__ __launch_bounds__(256) void edges_kernel(const float* __restrict__ lg,
                                                    const float* __restrict__ tptr,
                                                    float* __restrict__ out)
{
    int q = blockIdx.x * blockDim.x + threadIdx.x;
    if (q >= NQ) return;
    // diagonal zeros (poison-safe: every output element is written each call)
    if (q < BN * NNODE) {
        int bb = q >> 8, ii = q & 255;
        out[(bb << 16) | (ii << 8) | ii] = 0.0f;
    }
    float temp = fminf(fmaxf(tptr[0], 0.1f), 2.0f);

    int b = q / NPAIR;
    int p = q - b * NPAIR;
    double disc = 261121.0 - 8.0 * (double)p;  // 511^2 - 8p
    int i = (int)((511.0 - sqrt(disc)) * 0.5);
    if (i < 0) i = 0;
    if (i > NNODE - 2) i = NNODE - 2;
    while (rowbase(i + 1) <= p) ++i;
    while (rowbase(i) > p) --i;
    int j = p - rowbase(i) + i + 1;

    uint32_t w0 = bits_partitionable((uint32_t)(2 * q));
    uint32_t w1 = bits_partitionable((uint32_t)(2 * q + 1));

    float u0 = bits_to_u(w0), u1 = bits_to_u(w1);
    float g0 = (float)(-log(-log((double)u0)));
    float g1 = (float)(-log(-log((double)u1)));
    float l0 = lg[2 * b], l1 = lg[2 * b + 1];
    float A0 = (l0 + g0) / temp, A1 = (l1 + g1) / temp;
    float mx = fmaxf(A0, A1);
    float e0 = expf(A0 - mx), e1 = expf(A1 - mx);
    float ssum = e0 + e1;
    float y0 = e0 / ssum, y1 = e1 / ssum;
    float xe = (y0 >= y1) ? 1.0f : 0.0f;
    out[(b << 16) | (i << 8) | j] = xe;
    out[(b << 16) | (j << 8) | i] = xe;
}

extern "C" void kernel_launch(void* const* d_in, const int* in_sizes, int n_in,
                              void* d_out, int out_size, void* d_ws, size_t ws_size,
                              hipStream_t stream)
{
    const float* x    = (const float*)d_in[0];
    const float* st   = (const float*)d_in[1];
    const float* ipw  = (const float*)d_in[2];
    const float* ipb  = (const float*)d_in[3];
    const float* ipg  = (const float*)d_in[4];
    const float* ipbb = (const float*)d_in[5];
    const float* drw  = (const float*)d_in[6];
    const float* drb  = (const float*)d_in[7];
    const float* drg  = (const float*)d_in[8];
    const float* drbb = (const float*)d_in[9];
    const float* r1w  = (const float*)d_in[10];
    const float* r1b  = (const float*)d_in[11];
    const float* r2w  = (const float*)d_in[12];
    const float* r2b  = (const float*)d_in[13];
    const float* n1g  = (const float*)d_in[14];
    const float* n1b  = (const float*)d_in[15];
    const float* n2g  = (const float*)d_in[16];
    const float* n2b  = (const float*)d_in[17];
    // d_in[18] attn_w, d_in[19] attn_b: unused (softmax over identical nodes is uniform)
    const float* e1w  = (const float*)d_in[20];
    const float* e1b  = (const float*)d_in[21];
    const float* eg   = (const float*)d_in[22];
    const float* eb   = (const float*)d_in[23];
    const float* e2w  = (const float*)d_in[24];
    const float* e2b  = (const float*)d_in[25];
    const float* temp = (const float*)d_in[26];
    float* out = (float*)d_out;
    float* lg  = (float*)d_ws;   // 32 floats: per-batch logits

    hipLaunchKernelGGL(logits_kernel, dim3(BN), dim3(1024), 0, stream,
        x, st, ipw, ipb, ipg, ipbb, drw, drb, drg, drbb,
        r1w, r1b, r2w, r2b, n1g, n1b, n2g, n2b,
        e1w, e1b, eg, eb, e2w, e2b, lg);
    hipLaunchKernelGGL(edges_kernel, dim3((NQ + 255) / 256), dim3(256), 0, stream,
        lg, temp, out);
}

// Round 6
// 29.536 us; speedup vs baseline: 1.1917x; 1.1917x over previous
//
#include <hip/hip_runtime.h>
#include <stdint.h>
#include <math.h>

#define BN 16
#define LATN 64
#define STATSN 7
#define ZN 71
#define HN 128
#define H2N 256
#define NNODE 256
#define NPAIR 32640            // N*(N-1)/2
#define NQ 522240              // BN*NPAIR

// Raw barrier: drain LDS only (lgkmcnt); leave global prefetches in flight.
#define BARRIER() asm volatile("s_waitcnt lgkmcnt(0)\n\ts_barrier" ::: "memory")

// ---------------- Threefry-2x32, 20 rounds, key = (0, 42) ----------------
__device__ __forceinline__ void tf2x32(uint32_t x0, uint32_t x1,
                                       uint32_t& o0, uint32_t& o1) {
    const uint32_t ks0 = 0u, ks1 = 42u, ks2 = 0x1BD11BF0u;  // 0^42^0x1BD11BDA
    x0 += ks0; x1 += ks1;
#define TFRND(r) { x0 += x1; x1 = (x1 << (r)) | (x1 >> (32 - (r))); x1 ^= x0; }
    TFRND(13) TFRND(15) TFRND(26) TFRND(6)
    x0 += ks1; x1 += ks2 + 1u;
    TFRND(17) TFRND(29) TFRND(16) TFRND(24)
    x0 += ks2; x1 += ks0 + 2u;
    TFRND(13) TFRND(15) TFRND(26) TFRND(6)
    x0 += ks0; x1 += ks1 + 3u;
    TFRND(17) TFRND(29) TFRND(16) TFRND(24)
    x0 += ks1; x1 += ks2 + 4u;
    TFRND(13) TFRND(15) TFRND(26) TFRND(6)
    x0 += ks2; x1 += ks0 + 5u;
#undef TFRND
    o0 = x0; o1 = x1;
}

__device__ __forceinline__ uint32_t bits_partitionable(uint32_t m) {
    uint32_t o0, o1;
    tf2x32(0u, m, o0, o1);
    return o0 ^ o1;
}

__device__ __forceinline__ float bits_to_u(uint32_t w) {
    float f = __uint_as_float((w >> 9) | 0x3f800000u) - 1.0f;
    const float mn = 1e-9f;
    return fmaxf(mn, f * (1.0f - mn) + mn);
}

// ---------------- register-resident weight slice ----------------
template<int K, int O>
struct WSlice {
    static constexpr int C    = 1024 / O;
    static constexpr int KC   = (K + C - 1) / C;
    static constexpr int LOGO = (O == 256) ? 8 : 7;
    float w[KC];
    __device__ __forceinline__ void load(const float* __restrict__ W, int t) {
        const int out = t & (O - 1);
        const int k0 = (t >> LOGO) * KC;
#pragma unroll
        for (int i = 0; i < KC; ++i) {
            const int k = k0 + i;
            w[i] = ((K % C == 0) || k < K) ? W[k * O + out] : 0.0f;
        }
    }
    // identical fma pairing + summation order to the verified round-3 mm()
    __device__ __forceinline__ double dot(const float* __restrict__ vin, int t) const {
        const int k0 = (t >> LOGO) * KC;
        double a0 = 0.0, a1 = 0.0;
#pragma unroll
        for (int i = 0; i < KC; i += 2) {
            a0 = fma((double)vin[k0 + i], (double)w[i], a0);
            if (i + 1 < KC) a1 = fma((double)vin[k0 + i + 1], (double)w[i + 1], a1);
        }
        return a0 + a1;
    }
    __device__ __forceinline__ double dot_mask127(const float* __restrict__ vin, int t) const {
        const int k0 = (t >> LOGO) * KC;
        double a0 = 0.0, a1 = 0.0;
#pragma unroll
        for (int i = 0; i < KC; i += 2) {
            a0 = fma((double)vin[(k0 + i) & 127], (double)w[i], a0);
            if (i + 1 < KC) a1 = fma((double)vin[(k0 + i + 1) & 127], (double)w[i + 1], a1);
        }
        return a0 + a1;
    }
};

// wave-0-only: butterfly stats over NV values/lane; every lane gets (m, rs).
template<int NV>
__device__ __forceinline__ void w0_stats(const float* v, double& m, double& rs) {
    double a = 0.0, q = 0.0;
#pragma unroll
    for (int i = 0; i < NV; ++i) {
        a += (double)v[i];
        q += (double)v[i] * (double)v[i];
    }
#pragma unroll
    for (int s = 1; s < 64; s <<= 1) {
        a += __shfl_xor(a, s, 64);
        q += __shfl_xor(q, s, 64);
    }
    constexpr double O = (double)(NV * 64);
    m = a * (1.0 / O);
    const double var = q * (1.0 / O) - m * m;
    rs = 1.0 / sqrt(var + 1e-5);
}

__global__ __launch_bounds__(1024) void logits_kernel(
    const float* __restrict__ x, const float* __restrict__ st,
    const float* __restrict__ ipw, const float* __restrict__ ipb,
    const float* __restrict__ ipg, const float* __restrict__ ipbb,
    const float* __restrict__ drw, const float* __restrict__ drb,
    const float* __restrict__ drg, const float* __restrict__ drbb,
    const float* __restrict__ r1w, const float* __restrict__ r1b,
    const float* __restrict__ r2w, const float* __restrict__ r2b,
    const float* __restrict__ n1g, const float* __restrict__ n1b,
    const float* __restrict__ n2g, const float* __restrict__ n2b,
    const float* __restrict__ e1w, const float* __restrict__ e1b,
    const float* __restrict__ eg,  const float* __restrict__ eb,
    const float* __restrict__ e2w, const float* __restrict__ e2b,
    float* __restrict__ out_logits)
{
    __shared__ float V0[H2N];
    __shared__ float V1[H2N];
    __shared__ double dpart[1024];
    const int t = threadIdx.x;
    const int b = blockIdx.x;
    const int lane = t & 63;
    const bool w0 = (t < 64);

    // -------- prologue: issue all weight/param prefetches, stage z --------
    WSlice<ZN, H2N> w_ip;  w_ip.load(ipw, t);
    const float e2w_r = e2w[t & 255];

    // wave-0-only parameter registers (o = lane + 64*i)
    float ipb4[4], ipg4[4], ipbb4[4];
    float drb2[2], drg2[2], drbb2[2];
    float b1a2[2], g1a2[2], c1a2[2], g2a2[2], c2a2[2], b2a2[2];
    float b1b2[2], g1b2[2], c1b2[2], g2b2[2], c2b2[2], b2b2[2];
    float e1b2[2], eg2[2], eb2[2];
    if (w0) {
#pragma unroll
        for (int i = 0; i < 4; ++i) {
            const int o = lane + 64 * i;
            ipb4[i] = ipb[o]; ipg4[i] = ipg[o]; ipbb4[i] = ipbb[o];
        }
#pragma unroll
        for (int i = 0; i < 2; ++i) {
            const int o = lane + 64 * i;
            drb2[i] = drb[o]; drg2[i] = drg[o]; drbb2[i] = drbb[o];
            b1a2[i] = r1b[o];        g1a2[i] = n1g[o];        c1a2[i] = n1b[o];
            g2a2[i] = n2g[o];        c2a2[i] = n2b[o];        b2a2[i] = r2b[o];
            b1b2[i] = r1b[128 + o];  g1b2[i] = n1g[128 + o];  c1b2[i] = n1b[128 + o];
            g2b2[i] = n2g[128 + o];  c2b2[i] = n2b[128 + o];  b2b2[i] = r2b[128 + o];
            e1b2[i] = e1b[o]; eg2[i] = eg[o]; eb2[i] = eb[o];
        }
    }

    if (t < LATN)      V0[t] = x[b * LATN + t];
    else if (t < ZN)   V0[t] = st[b * STATSN + (t - LATN)];
    else if (t < H2N)  V0[t] = 0.0f;   // zero-pad for padded w entries
    BARRIER();

    // -------- input_proj: [71]->relu->LN(256) -> V1 --------
    WSlice<H2N, HN> w_dr;  w_dr.load(drw, t);   // prefetch
    dpart[t] = w_ip.dot(V0, t);
    BARRIER();
    if (w0) {
        float v4[4];
#pragma unroll
        for (int i = 0; i < 4; ++i) {
            const int o = lane + 64 * i;
            double ca = 0.0;
#pragma unroll
            for (int cc = 0; cc < WSlice<ZN, H2N>::C; ++cc) ca += dpart[o + cc * H2N];
            v4[i] = fmaxf((float)ca + ipb4[i], 0.0f);
        }
        double m, rs; w0_stats<4>(v4, m, rs);
#pragma unroll
        for (int i = 0; i < 4; ++i) {
            const int o = lane + 64 * i;
            float r = (float)(((double)v4[i] - m) * rs);
            V1[o] = r * ipg4[i] + ipbb4[i];
        }
    }
    BARRIER();

    // -------- dim_reduce: [256]->[128], relu, LN -> V0 --------
    WSlice<HN, HN> w_r1a;  w_r1a.load(r1w, t);   // prefetch
    dpart[t] = w_dr.dot(V1, t);
    BARRIER();
    if (w0) {
        float v2[2];
#pragma unroll
        for (int i = 0; i < 2; ++i) {
            const int o = lane + 64 * i;
            double ca = 0.0;
#pragma unroll
            for (int cc = 0; cc < WSlice<H2N, HN>::C; ++cc) ca += dpart[o + cc * HN];
            v2[i] = fmaxf((float)ca + drb2[i], 0.0f);
        }
        double m, rs; w0_stats<2>(v2, m, rs);
#pragma unroll
        for (int i = 0; i < 2; ++i) {
            const int o = lane + 64 * i;
            float r = (float)(((double)v2[i] - m) * rs);
            V0[o] = r * drg2[i] + drbb2[i];
        }
    }
    BARRIER();

    // -------- residual block 0 --------
    WSlice<HN, HN> w_r2a;  w_r2a.load(r2w, t);   // prefetch
    if (w0) {   // LN1 (stats over h = V0, single barrier)
        float h2[2];
#pragma unroll
        for (int i = 0; i < 2; ++i) h2[i] = V0[lane + 64 * i];
        double m, rs; w0_stats<2>(h2, m, rs);
#pragma unroll
        for (int i = 0; i < 2; ++i) {
            const int o = lane + 64 * i;
            float r = (float)(((double)h2[i] - m) * rs);
            V1[o] = r * g1a2[i] + c1a2[i];
        }
    }
    BARRIER();
    WSlice<HN, HN> w_r1b;  w_r1b.load(r1w + HN * HN, t);   // prefetch
    dpart[t] = w_r1a.dot(V1, t);      // lin1
    BARRIER();
    if (w0) {   // relu + LN2
        float v2[2];
#pragma unroll
        for (int i = 0; i < 2; ++i) {
            const int o = lane + 64 * i;
            double ca = 0.0;
#pragma unroll
            for (int cc = 0; cc < WSlice<HN, HN>::C; ++cc) ca += dpart[o + cc * HN];
            v2[i] = fmaxf((float)ca + b1a2[i], 0.0f);
        }
        double m, rs; w0_stats<2>(v2, m, rs);
#pragma unroll
        for (int i = 0; i < 2; ++i) {
            const int o = lane + 64 * i;
            float r = (float)(((double)v2[i] - m) * rs);
            V1[o] = r * g2a2[i] + c2a2[i];
        }
    }
    BARRIER();
    WSlice<HN, HN> w_r2b;  w_r2b.load(r2w + HN * HN, t);   // prefetch
    dpart[t] = w_r2a.dot(V1, t);      // lin2
    BARRIER();
    if (w0) {   // residual
#pragma unroll
        for (int i = 0; i < 2; ++i) {
            const int o = lane + 64 * i;
            double ca = 0.0;
#pragma unroll
            for (int cc = 0; cc < WSlice<HN, HN>::C; ++cc) ca += dpart[o + cc * HN];
            float r2o = (float)ca + b2a2[i];
            float h = V0[o];
            V0[o] = h + 0.1f * (r2o + h);
        }
    }
    BARRIER();

    // -------- residual block 1 --------
    if (w0) {   // LN1
        float h2[2];
#pragma unroll
        for (int i = 0; i < 2; ++i) h2[i] = V0[lane + 64 * i];
        double m, rs; w0_stats<2>(h2, m, rs);
#pragma unroll
        for (int i = 0; i < 2; ++i) {
            const int o = lane + 64 * i;
            float r = (float)(((double)h2[i] - m) * rs);
            V1[o] = r * g1b2[i] + c1b2[i];
        }
    }
    BARRIER();
    WSlice<H2N, HN> w_e1;  w_e1.load(e1w, t);   // prefetch edge MLP
    dpart[t] = w_r1b.dot(V1, t);      // lin1
    BARRIER();
    if (w0) {   // relu + LN2
        float v2[2];
#pragma unroll
        for (int i = 0; i < 2; ++i) {
            const int o = lane + 64 * i;
            double ca = 0.0;
#pragma unroll
            for (int cc = 0; cc < WSlice<HN, HN>::C; ++cc) ca += dpart[o + cc * HN];
            v2[i] = fmaxf((float)ca + b1b2[i], 0.0f);
        }
        double m, rs; w0_stats<2>(v2, m, rs);
#pragma unroll
        for (int i = 0; i < 2; ++i) {
            const int o = lane + 64 * i;
            float r = (float)(((double)v2[i] - m) * rs);
            V1[o] = r * g2b2[i] + c2b2[i];
        }
    }
    BARRIER();
    dpart[t] = w_r2b.dot(V1, t);      // lin2
    BARRIER();
    if (w0) {   // residual
#pragma unroll
        for (int i = 0; i < 2; ++i) {
            const int o = lane + 64 * i;
            double ca = 0.0;
#pragma unroll
            for (int cc = 0; cc < WSlice<HN, HN>::C; ++cc) ca += dpart[o + cc * HN];
            float r2o = (float)ca + b2b2[i];
            float h = V0[o];
            V0[o] = h + 0.1f * (r2o + h);
        }
    }
    BARRIER();

    // -------- attention uniform (exact 1/256) + edge MLP e1 --------
    dpart[t] = w_e1.dot_mask127(V0, t) * 0.00390625;
    BARRIER();
    if (w0) {
        float v2[2];
#pragma unroll
        for (int i = 0; i < 2; ++i) {
            const int o = lane + 64 * i;
            double ca = 0.0;
#pragma unroll
            for (int cc = 0; cc < WSlice<H2N, HN>::C; ++cc) ca += dpart[o + cc * HN];
            v2[i] = fmaxf((float)ca + e1b2[i], 0.0f);
        }
        double m, rs; w0_stats<2>(v2, m, rs);
#pragma unroll
        for (int i = 0; i < 2; ++i) {
            const int o = lane + 64 * i;
            float r = (float)(((double)v2[i] - m) * rs);
            V0[o] = r * eg2[i] + eb2[i];
        }
    }
    BARRIER();

    // -------- e2: [128]->[2] (identical arithmetic to round 3/4) --------
    {
        if (t < 256) {
            const int c = t >> 1;
            double p = (double)V0[c] * (double)e2w_r;
#pragma unroll
            for (int s = 32; s > 1; s >>= 1) p += __shfl_down(p, s, 64);
            const int wid = t >> 6, ln = t & 63;
            if (ln < 2) dpart[wid * 2 + ln] = p;
        }
        BARRIER();
        if (t < 2) {
            double acc = 0.0;
#pragma unroll
            for (int c2 = 0; c2 < 4; ++c2) acc += dpart[c2 * 2 + t];
            out_logits[b * 2 + t] = (float)acc + e2b[t];
        }
    }
}

// ---------------- per-pair gumbel decisions + scatter ----------------
__device__ __forceinline__ int rowbase(int i) { return (i * (2 * NNODE - 1 - i)) >> 1; }

__global__ __launch_bounds__(256) void edges_kernel(const float* __restrict__ lg,
                                                    const float* __restrict__ tptr,
                                                    float* __restrict__ out)
{
    int q = blockIdx.x * blockDim.x + threadIdx.x;
    if (q >= NQ) return;
    // diagonal zeros (poison-safe: every output element is written each call)
    if (q < BN * NNODE) {
        int bb = q >> 8, ii = q & 255;
        out[(bb << 16) | (ii << 8) | ii] = 0.0f;
    }
    float temp = fminf(fmaxf(tptr[0], 0.1f), 2.0f);

    int b = q / NPAIR;
    int p = q - b * NPAIR;
    double disc = 261121.0 - 8.0 * (double)p;  // 511^2 - 8p
    int i = (int)((511.0 - sqrt(disc)) * 0.5);
    if (i < 0) i = 0;
    if (i > NNODE - 2) i = NNODE - 2;
    while (rowbase(i + 1) <= p) ++i;
    while (rowbase(i) > p) --i;
    int j = p - rowbase(i) + i + 1;

    uint32_t w0 = bits_partitionable((uint32_t)(2 * q));
    uint32_t w1 = bits_partitionable((uint32_t)(2 * q + 1));

    float u0 = bits_to_u(w0), u1 = bits_to_u(w1);
    float g0 = (float)(-log(-log((double)u0)));
    float g1 = (float)(-log(-log((double)u1)));
    float l0 = lg[2 * b], l1 = lg[2 * b + 1];
    float A0 = (l0 + g0) / temp, A1 = (l1 + g1) / temp;
    float mx = fmaxf(A0, A1);
    float e0 = expf(A0 - mx), e1 = expf(A1 - mx);
    float ssum = e0 + e1;
    float y0 = e0 / ssum, y1 = e1 / ssum;
    float xe = (y0 >= y1) ? 1.0f : 0.0f;
    out[(b << 16) | (i << 8) | j] = xe;
    out[(b << 16) | (j << 8) | i] = xe;
}

extern "C" void kernel_launch(void* const* d_in, const int* in_sizes, int n_in,
                              void* d_out, int out_size, void* d_ws, size_t ws_size,
                              hipStream_t stream)
{
    const float* x    = (const float*)d_in[0];
    const float* st   = (const float*)d_in[1];
    const float* ipw  = (const float*)d_in[2];
    const float* ipb  = (const float*)d_in[3];
    const float* ipg  = (const float*)d_in[4];
    const float* ipbb = (const float*)d_in[5];
    const float* drw  = (const float*)d_in[6];
    const float* drb  = (const float*)d_in[7];
    const float* drg  = (const float*)d_in[8];
    const float* drbb = (const float*)d_in[9];
    const float* r1w  = (const float*)d_in[10];
    const float* r1b  = (const float*)d_in[11];
    const float* r2w  = (const float*)d_in[12];
    const float* r2b  = (const float*)d_in[13];
    const float* n1g  = (const float*)d_in[14];
    const float* n1b  = (const float*)d_in[15];
    const float* n2g  = (const float*)d_in[16];
    const float* n2b  = (const float*)d_in[17];
    // d_in[18] attn_w, d_in[19] attn_b: unused (softmax over identical nodes is uniform)
    const float* e1w  = (const float*)d_in[20];
    const float* e1b  = (const float*)d_in[21];
    const float* eg   = (const float*)d_in[22];
    const float* eb   = (const float*)d_in[23];
    const float* e2w  = (const float*)d_in[24];
    const float* e2b  = (const float*)d_in[25];
    const float* temp = (const float*)d_in[26];
    float* out = (float*)d_out;
    float* lg  = (float*)d_ws;   // 32 floats: per-batch logits

    hipLaunchKernelGGL(logits_kernel, dim3(BN), dim3(1024), 0, stream,
        x, st, ipw, ipb, ipg, ipbb, drw, drb, drg, drbb,
        r1w, r1b, r2w, r2b, n1g, n1b, n2g, n2b,
        e1w, e1b, eg, eb, e2w, e2b, lg);
    hipLaunchKernelGGL(edges_kernel, dim3((NQ + 255) / 256), dim3(256), 0, stream,
        lg, temp, out);
}